// Round 4
// baseline (253.801 us; speedup 1.0000x reference)
//
#include <hip/hip_runtime.h>
#include <math.h>

#define N_ROWS 32768
#define D 256
#define C 16

// workspace layout in floats
#define WS_SUMS_A 0
#define WS_SQ_A   4096
#define WS_SUMS_B 8192
#define WS_SQ_B   12288
#define WS_INV    16384
#define WS_COV    16385
#define WS_COUNTS 16392   /* int[16] */
#define WS_CURSOR 16408   /* int[16] */
#define WS_POFFP  16424   /* int[17] padded-panel offsets */
#define WS_PERM   16640   /* int[32768] */
#define WS_ZERO_FLOATS 16408

#define MAXPAN   1040     /* >= sum_c ceil(cnt_c/32) (<=1039) */
#define PANEL_DW 5120     /* 256 cols * 20 dwords (16 data + 4 pad) */

#define WS_PSUM   49408                      /* [MAXPAN][4][256] f32 partial stats */
#define PSUM_SZ   (MAXPAN * 1024)
#define WS_PANELS (WS_PSUM + PSUM_SZ)        /* 1,114,368 */
#define WS_GPART  (WS_PANELS + 2 * MAXPAN * PANEL_DW)   /* 11,763,968 */
#define GP_TILE   16384
#define GP_PER_SPLIT (3 * C * 2 * GP_TILE)   /* 1,572,864 floats */
#define NSPLIT    8

#define NEED_A ((size_t)(WS_GPART + NSPLIT * GP_PER_SPLIT) * 4)   /* ~97.4 MB */
#define NEED_C ((size_t)WS_GPART * 4)                              /* ~47.1 MB */

typedef __attribute__((ext_vector_type(8))) __bf16 bf16x8;
typedef __attribute__((ext_vector_type(16))) float f32x16;

__device__ inline unsigned bf16_rne(float f) {
    unsigned u = __float_as_uint(f);
    return (u + 0x7fffu + ((u >> 16) & 1u)) >> 16;
}
__device__ inline unsigned pack_bf16(float lo, float hi) {
    return bf16_rne(lo) | (bf16_rne(hi) << 16);
}

__global__ __launch_bounds__(256) void k_hist(const int* __restrict__ labels,
                                              int* __restrict__ counts) {
    __shared__ int h[C];
    const int t = threadIdx.x;
    if (t < C) h[t] = 0;
    __syncthreads();
    const int i = blockIdx.x * 256 + t;
    atomicAdd(&h[labels[i]], 1);
    __syncthreads();
    if (t < C) atomicAdd(&counts[t], h[t]);
}

__global__ void k_scan(const int* __restrict__ counts, int* __restrict__ cursor,
                       int* __restrict__ poffp) {
    if (threadIdx.x == 0) {
        int off = 0, po = 0;
        for (int c = 0; c < C; ++c) {
            cursor[c] = off;
            poffp[c] = po;
            off += counts[c];
            po += (counts[c] + 31) >> 5;
        }
        poffp[C] = po;
    }
}

__global__ __launch_bounds__(256) void k_scatter(const int* __restrict__ labels,
                                                 int* __restrict__ cursor,
                                                 int* __restrict__ perm) {
    __shared__ int lh[C];
    __shared__ int lbase[C];
    const int t = threadIdx.x;
    if (t < C) lh[t] = 0;
    __syncthreads();
    const int i = blockIdx.x * 256 + t;
    const int lab = labels[i];
    const int lr = atomicAdd(&lh[lab], 1);
    __syncthreads();
    if (t < C) lbase[t] = atomicAdd(&cursor[t], lh[t]);
    __syncthreads();
    perm[lbase[lab] + lr] = i;
}

// One block per (class, 32-row kstep) panel. Gathers 32 rows of BOTH inputs,
// writes the bf16 MFMA panel image + per-block stat partials (NO contended
// atomics), and accumulates inv_loss.
__global__ __launch_bounds__(256) void k_pack(const float* __restrict__ za,
                                              const float* __restrict__ zb,
                                              const int* __restrict__ perm,
                                              const int* __restrict__ counts,
                                              const int* __restrict__ poffp,
                                              float* __restrict__ ws) {
    const int t = threadIdx.x;
    const int blk = blockIdx.x;
    __shared__ int sh[4];
    __shared__ __align__(16) float T[32][261];   // +5 pad: 2-way on write (free)
    if (t == 0) {
        int c = 0;
        while (c < C && poffp[c + 1] <= blk) ++c;
        int eoff = 0;
        for (int i = 0; i < c && i < C; ++i) eoff += counts[i];
        sh[0] = c;
        sh[1] = (c < C) ? (blk - poffp[c]) : 0;
        sh[2] = eoff;
        sh[3] = (c < C) ? counts[c] : 0;
    }
    __syncthreads();
    const int cls = sh[0];
    if (cls >= C) return;
    const int kstep = sh[1], eoff = sh[2], cnt = sh[3];

    const int r = t >> 3, c8 = t & 7;            // 32 rows x 8 col-chunks
    const int lrow = kstep * 32 + r;
    const int src = (lrow < cnt) ? perm[eoff + lrow] : -1;

    float4 av[8];
    float invp = 0.f;
    unsigned* panels = (unsigned*)(ws + WS_PANELS);

    for (int ph = 0; ph < 2; ++ph) {
        const float* X = ph ? zb : za;
        float4 v[8];
        #pragma unroll
        for (int j = 0; j < 8; ++j) {
            if (src >= 0) v[j] = *(const float4*)(X + (size_t)src * D + (c8 + 8 * j) * 4);
            else v[j] = make_float4(0.f, 0.f, 0.f, 0.f);
        }
        if (ph == 0) {
            #pragma unroll
            for (int j = 0; j < 8; ++j) av[j] = v[j];
        } else {
            #pragma unroll
            for (int j = 0; j < 8; ++j) {
                const float dx = av[j].x - v[j].x, dy = av[j].y - v[j].y;
                const float dz = av[j].z - v[j].z, dw = av[j].w - v[j].w;
                invp += dx * dx + dy * dy + dz * dz + dw * dw;
            }
        }
        __syncthreads();   // prior phase's column-pass readers are done
        #pragma unroll
        for (int j = 0; j < 8; ++j)
            *(float4*)&T[r][4 * (c8 + 8 * j)] = v[j];
        __syncthreads();

        // column pass: thread t owns column t
        float s1 = 0.f, s2 = 0.f;
        unsigned pw[16];
        #pragma unroll
        for (int w = 0; w < 16; ++w) {
            const float x0 = T[2 * w][t], x1 = T[2 * w + 1][t];
            s1 += x0 + x1;
            s2 += x0 * x0 + x1 * x1;
            pw[w] = pack_bf16(x0, x1);
        }
        // contention-free stat partials
        ws[WS_PSUM + (size_t)blk * 1024 + (2 * ph + 0) * 256 + t] = s1;
        ws[WS_PSUM + (size_t)blk * 1024 + (2 * ph + 1) * 256 + t] = s2;
        // panel: write all 20 dwords (incl. pad) -> fully-lined stores
        unsigned* pan = panels + ((size_t)ph * MAXPAN + blk) * PANEL_DW + t * 20;
        *(uint4*)(pan + 0)  = make_uint4(pw[0],  pw[1],  pw[2],  pw[3]);
        *(uint4*)(pan + 4)  = make_uint4(pw[4],  pw[5],  pw[6],  pw[7]);
        *(uint4*)(pan + 8)  = make_uint4(pw[8],  pw[9],  pw[10], pw[11]);
        *(uint4*)(pan + 12) = make_uint4(pw[12], pw[13], pw[14], pw[15]);
        *(uint4*)(pan + 16) = make_uint4(0u, 0u, 0u, 0u);
    }
    for (int o = 32; o > 0; o >>= 1) invp += __shfl_down(invp, o, 64);
    if ((t & 63) == 0) atomicAdd(&ws[WS_INV], invp);
}

// Fold per-panel stat partials into the class stats (coalesced, no atomics).
__global__ __launch_bounds__(256) void k_reduce(const int* __restrict__ poffp,
                                                float* __restrict__ ws) {
    const int t = threadIdx.x;
    const int c = blockIdx.x, s = blockIdx.y;    // s: 0=sumA,1=sqA,2=sumB,3=sqB
    float acc = 0.f;
    const int p0 = poffp[c], p1 = poffp[c + 1];
    for (int p = p0; p < p1; ++p)
        acc += ws[WS_PSUM + (size_t)p * 1024 + s * 256 + t];
    const int base = (s == 0) ? WS_SUMS_A : (s == 1) ? WS_SQ_A
                   : (s == 2) ? WS_SUMS_B : WS_SQ_B;
    ws[base + c * D + t] = acc;
}

// Split-K MFMA Gram: each block accumulates a K-chunk of one 128x128 tile and
// writes its f32 partial (no atomics) to the GPART region.
__global__ __launch_bounds__(256) void k_gram_split(const int* __restrict__ poffp,
                                                    float* __restrict__ ws) {
    const int t = threadIdx.x;
    const int tile = blockIdx.x % 3;          // 0,1,2 -> (0,0),(0,1),(1,1)
    const int split = blockIdx.x / 3;
    const int tx = tile >> 1, ty = (tile + 1) >> 1;
    const int cls = blockIdx.y, inp = blockIdx.z;
    const int p0 = poffp[cls];
    const int nsteps = poffp[cls + 1] - p0;
    const int chunk = (nsteps + NSPLIT - 1) / NSPLIT;
    const int sb = split * chunk;
    const int se = min(sb + chunk, nsteps);
    const unsigned* panels = (const unsigned*)(ws + WS_PANELS)
                           + (size_t)(inp * MAXPAN + p0) * PANEL_DW;
    const int cm0 = tx * 128, cn0 = ty * 128;
    const bool diag = (tx == ty);

    __shared__ __align__(16) unsigned lds[2][2][2560];   // 40 KB

    const int lane = t & 63, w = t >> 6;
    const int wr = w & 1, wc = w >> 1;
    const int cg = lane & 31, q = lane >> 5;

    f32x16 acc[2][2];
    #pragma unroll
    for (int i = 0; i < 2; ++i)
        #pragma unroll
        for (int j = 0; j < 2; ++j) acc[i][j] = 0.0f;

    auto stage = [&](int buf, int s) {
        const unsigned* base = panels + (size_t)s * PANEL_DW;
        {
            const unsigned* srcp = base + cm0 * 20;
            for (int u = t; u < 640; u += 256)
                __builtin_amdgcn_global_load_lds(
                    (const __attribute__((address_space(1))) unsigned*)(srcp + u * 4),
                    (__attribute__((address_space(3))) unsigned*)(&lds[buf][0][u * 4]),
                    16, 0, 0);
        }
        if (!diag) {
            const unsigned* srcp = base + cn0 * 20;
            for (int u = t; u < 640; u += 256)
                __builtin_amdgcn_global_load_lds(
                    (const __attribute__((address_space(1))) unsigned*)(srcp + u * 4),
                    (__attribute__((address_space(3))) unsigned*)(&lds[buf][1][u * 4]),
                    16, 0, 0);
        }
    };

    const int bch = diag ? 0 : 1;
    if (sb < se) {
        stage(0, sb);
        __syncthreads();
        for (int s = sb; s < se; ++s) {
            const int buf = (s - sb) & 1;
            if (s + 1 < se) stage(buf ^ 1, s + 1);   // DMA overlaps compute
            #pragma unroll
            for (int h = 0; h < 2; ++h) {
                bf16x8 a0 = *(const bf16x8*)&lds[buf][0][(wr * 64 + cg) * 20 + h * 8 + q * 4];
                bf16x8 a1 = *(const bf16x8*)&lds[buf][0][(wr * 64 + 32 + cg) * 20 + h * 8 + q * 4];
                bf16x8 b0 = *(const bf16x8*)&lds[buf][bch][(wc * 64 + cg) * 20 + h * 8 + q * 4];
                bf16x8 b1 = *(const bf16x8*)&lds[buf][bch][(wc * 64 + 32 + cg) * 20 + h * 8 + q * 4];
                acc[0][0] = __builtin_amdgcn_mfma_f32_32x32x16_bf16(a0, b0, acc[0][0], 0, 0, 0);
                acc[0][1] = __builtin_amdgcn_mfma_f32_32x32x16_bf16(a0, b1, acc[0][1], 0, 0, 0);
                acc[1][0] = __builtin_amdgcn_mfma_f32_32x32x16_bf16(a1, b0, acc[1][0], 0, 0, 0);
                acc[1][1] = __builtin_amdgcn_mfma_f32_32x32x16_bf16(a1, b1, acc[1][1], 0, 0, 0);
            }
            __syncthreads();
        }
    }

    float* gp = ws + WS_GPART
              + ((size_t)(split * 3 + tile) * C * 2 + cls * 2 + inp) * GP_TILE;
    #pragma unroll
    for (int i = 0; i < 2; ++i)
        #pragma unroll
        for (int j = 0; j < 2; ++j)
            #pragma unroll
            for (int r = 0; r < 16; ++r) {
                const int row = wr * 64 + i * 32 + (r & 3) + 8 * (r >> 2) + 4 * q;
                const int col = wc * 64 + j * 32 + cg;
                gp[row * 128 + col] = acc[i][j][r];
            }
}

// Sum split partials, form cov, accumulate weighted off-diagonal cov^2.
__global__ __launch_bounds__(256) void k_cov(const int* __restrict__ counts,
                                             float* __restrict__ ws) {
    const int t = threadIdx.x;
    const int tile = blockIdx.x;
    const int tx = tile >> 1, ty = (tile + 1) >> 1;
    const int cls = blockIdx.y, inp = blockIdx.z;
    const int cnt = counts[cls];
    const float fc = (float)cnt;
    const float cinv = 1.f / fc, uinv = 1.f / (fc - 1.f);
    const float wgt = (tx == ty) ? 1.f : 2.f;
    const int cm0 = tx * 128, cn0 = ty * 128;
    __shared__ float M[D];
    const float* sums = ws + (inp ? WS_SUMS_B : WS_SUMS_A) + cls * D;
    M[t] = sums[t] * cinv;
    __syncthreads();

    const float* gp0 = ws + WS_GPART + ((size_t)tile * C * 2 + cls * 2 + inp) * GP_TILE;
    float local = 0.f;
    #pragma unroll 4
    for (int k = 0; k < 64; ++k) {
        const int e = k * 256 + t;
        float g = 0.f;
        #pragma unroll
        for (int s = 0; s < NSPLIT; ++s)
            g += gp0[(size_t)s * GP_PER_SPLIT + e];
        const int row = e >> 7, col = e & 127;
        const int gm = cm0 + row, gn = cn0 + col;
        const float cov = (g - fc * M[gm] * M[gn]) * uinv;
        if (gm != gn) local += wgt * cov * cov;
    }
    for (int o = 32; o > 0; o >>= 1) local += __shfl_down(local, o, 64);
    __shared__ float red[4];
    if ((t & 63) == 0) red[t >> 6] = local;
    __syncthreads();
    if (t == 0) atomicAdd(&ws[WS_COV], red[0] + red[1] + red[2] + red[3]);
}

// Full-K gram (tier C: ws too small for split partials) — round-3 version.
__global__ __launch_bounds__(256) void k_gram_fast(const int* __restrict__ counts,
                                                   const int* __restrict__ poffp,
                                                   float* __restrict__ ws) {
    const int t = threadIdx.x;
    const int tile = blockIdx.x;
    const int tx = tile >> 1, ty = (tile + 1) >> 1;
    const int cls = blockIdx.y, inp = blockIdx.z;
    const int cnt = counts[cls];
    const int p0 = poffp[cls];
    const int nsteps = poffp[cls + 1] - p0;
    if (nsteps == 0) return;
    const float* sums = ws + (inp ? WS_SUMS_B : WS_SUMS_A) + cls * D;
    const unsigned* panels = (const unsigned*)(ws + WS_PANELS)
                           + (size_t)(inp * MAXPAN + p0) * PANEL_DW;
    const int cm0 = tx * 128, cn0 = ty * 128;
    const bool diag = (tx == ty);
    __shared__ __align__(16) unsigned lds[2][2][2560];
    const int lane = t & 63, w = t >> 6;
    const int wr = w & 1, wc = w >> 1;
    const int cg = lane & 31, q = lane >> 5;
    f32x16 acc[2][2];
    #pragma unroll
    for (int i = 0; i < 2; ++i)
        #pragma unroll
        for (int j = 0; j < 2; ++j) acc[i][j] = 0.0f;
    auto stage = [&](int buf, int s) {
        const unsigned* base = panels + (size_t)s * PANEL_DW;
        {
            const unsigned* srcp = base + cm0 * 20;
            for (int u = t; u < 640; u += 256)
                __builtin_amdgcn_global_load_lds(
                    (const __attribute__((address_space(1))) unsigned*)(srcp + u * 4),
                    (__attribute__((address_space(3))) unsigned*)(&lds[buf][0][u * 4]),
                    16, 0, 0);
        }
        if (!diag) {
            const unsigned* srcp = base + cn0 * 20;
            for (int u = t; u < 640; u += 256)
                __builtin_amdgcn_global_load_lds(
                    (const __attribute__((address_space(1))) unsigned*)(srcp + u * 4),
                    (__attribute__((address_space(3))) unsigned*)(&lds[buf][1][u * 4]),
                    16, 0, 0);
        }
    };
    const int bch = diag ? 0 : 1;
    stage(0, 0);
    __syncthreads();
    for (int s = 0; s < nsteps; ++s) {
        const int buf = s & 1;
        if (s + 1 < nsteps) stage(buf ^ 1, s + 1);
        #pragma unroll
        for (int h = 0; h < 2; ++h) {
            bf16x8 a0 = *(const bf16x8*)&lds[buf][0][(wr * 64 + cg) * 20 + h * 8 + q * 4];
            bf16x8 a1 = *(const bf16x8*)&lds[buf][0][(wr * 64 + 32 + cg) * 20 + h * 8 + q * 4];
            bf16x8 b0 = *(const bf16x8*)&lds[buf][bch][(wc * 64 + cg) * 20 + h * 8 + q * 4];
            bf16x8 b1 = *(const bf16x8*)&lds[buf][bch][(wc * 64 + 32 + cg) * 20 + h * 8 + q * 4];
            acc[0][0] = __builtin_amdgcn_mfma_f32_32x32x16_bf16(a0, b0, acc[0][0], 0, 0, 0);
            acc[0][1] = __builtin_amdgcn_mfma_f32_32x32x16_bf16(a0, b1, acc[0][1], 0, 0, 0);
            acc[1][0] = __builtin_amdgcn_mfma_f32_32x32x16_bf16(a1, b0, acc[1][0], 0, 0, 0);
            acc[1][1] = __builtin_amdgcn_mfma_f32_32x32x16_bf16(a1, b1, acc[1][1], 0, 0, 0);
        }
        __syncthreads();
    }
    const float fc = (float)cnt;
    const float cinv = 1.f / fc, uinv = 1.f / (fc - 1.f);
    const float wgt = diag ? 1.f : 2.f;
    float local = 0.f;
    #pragma unroll
    for (int i = 0; i < 2; ++i) {
        #pragma unroll
        for (int j = 0; j < 2; ++j) {
            const int gn = cn0 + wc * 64 + j * 32 + (lane & 31);
            const float mn = sums[gn] * cinv;
            #pragma unroll
            for (int r = 0; r < 16; ++r) {
                const int row = (r & 3) + 8 * (r >> 2) + 4 * q;
                const int gm = cm0 + wr * 64 + i * 32 + row;
                const float cov = (acc[i][j][r] - fc * (sums[gm] * cinv) * mn) * uinv;
                if (gm != gn) local += wgt * cov * cov;
            }
        }
    }
    for (int o = 32; o > 0; o >>= 1) local += __shfl_down(local, o, 64);
    if (lane == 0) atomicAdd(&ws[WS_COV], local);
}

// ---------------- tier D fallback (tiny ws): round-2 kernels ----------------
__global__ __launch_bounds__(256) void k_stats(const float* __restrict__ za,
                                               const float* __restrict__ zb,
                                               const int* __restrict__ labels,
                                               float* __restrict__ ws) {
    const int t = threadIdx.x;
    __shared__ float S[4][C * D];
    __shared__ int lab[512];
    for (int i = t; i < 4 * C * D; i += 256) ((float*)S)[i] = 0.f;
    const int r0 = blockIdx.x * 512;
    for (int i = t; i < 512; i += 256) lab[i] = labels[r0 + i];
    __syncthreads();
    float invp = 0.f;
    #pragma unroll 4
    for (int rr = 0; rr < 512; ++rr) {
        const int l = lab[rr];
        const float a = za[(size_t)(r0 + rr) * D + t];
        const float b = zb[(size_t)(r0 + rr) * D + t];
        const float dd = a - b;
        invp += dd * dd;
        S[0][l * D + t] += a;
        S[1][l * D + t] += a * a;
        S[2][l * D + t] += b;
        S[3][l * D + t] += b * b;
    }
    __syncthreads();
    #pragma unroll
    for (int c = 0; c < C; ++c) {
        atomicAdd(&ws[WS_SUMS_A + c * D + t], S[0][c * D + t]);
        atomicAdd(&ws[WS_SQ_A   + c * D + t], S[1][c * D + t]);
        atomicAdd(&ws[WS_SUMS_B + c * D + t], S[2][c * D + t]);
        atomicAdd(&ws[WS_SQ_B   + c * D + t], S[3][c * D + t]);
    }
    for (int o = 32; o > 0; o >>= 1) invp += __shfl_down(invp, o, 64);
    if ((t & 63) == 0) atomicAdd(&ws[WS_INV], invp);
}

#define STR 20
#define KB 32
__global__ __launch_bounds__(256) void k_gram_slow(const float* __restrict__ za,
                                                   const float* __restrict__ zb,
                                                   const int* __restrict__ perm,
                                                   const int* __restrict__ counts,
                                                   float* __restrict__ ws) {
    const int t = threadIdx.x;
    const int tile = blockIdx.x;
    const int tx = tile >> 1, ty = (tile + 1) >> 1;
    const int cls = blockIdx.y;
    const int inp = blockIdx.z;
    const float* X = inp ? zb : za;
    const float* sums = ws + (inp ? WS_SUMS_B : WS_SUMS_A) + cls * D;
    int offs = 0;
    for (int c = 0; c < cls; ++c) offs += counts[c];
    const int cnt = counts[cls];
    const int cm0 = tx * 128, cn0 = ty * 128;
    __shared__ __align__(16) unsigned lds[2][256 * STR];
    const int p = t >> 5, cq = t & 31;
    const int lane = t & 63, w = t >> 6;
    const int wr = w & 1, wc = w >> 1;
    const int cg = lane & 31, q = lane >> 5;
    f32x16 acc[2][2];
    #pragma unroll
    for (int i = 0; i < 2; ++i)
        #pragma unroll
        for (int j = 0; j < 2; ++j) acc[i][j] = 0.0f;
    const int nsteps = (cnt + KB - 1) / KB;
    auto stage = [&](int buf, int k0) {
        #pragma unroll
        for (int ch = 0; ch < 2; ++ch) {
            const int gc = (ch ? cn0 : cm0) + 4 * cq;
            #pragma unroll
            for (int sub = 0; sub < 2; ++sub) {
                const int rr = sub * 16 + 2 * p;
                const int r0 = k0 + rr, r1 = r0 + 1;
                float4 v0 = make_float4(0.f, 0.f, 0.f, 0.f), v1 = v0;
                if (r0 < cnt) v0 = *(const float4*)(X + (size_t)perm[offs + r0] * D + gc);
                if (r1 < cnt) v1 = *(const float4*)(X + (size_t)perm[offs + r1] * D + gc);
                unsigned* dst = &lds[buf][(ch * 128 + 4 * cq) * STR + (rr >> 1)];
                dst[0 * STR] = pack_bf16(v0.x, v1.x);
                dst[1 * STR] = pack_bf16(v0.y, v1.y);
                dst[2 * STR] = pack_bf16(v0.z, v1.z);
                dst[3 * STR] = pack_bf16(v0.w, v1.w);
            }
        }
    };
    auto frag = [&](int buf, int colbase, int h) -> bf16x8 {
        return *(const bf16x8*)&lds[buf][(colbase + cg) * STR + h * 8 + q * 4];
    };
    stage(0, 0);
    for (int s = 0; s < nsteps; ++s) {
        __syncthreads();
        const int buf = s & 1;
        if (s + 1 < nsteps) stage(buf ^ 1, (s + 1) * KB);
        #pragma unroll
        for (int h = 0; h < 2; ++h) {
            bf16x8 a0 = frag(buf, wr * 64, h);
            bf16x8 a1 = frag(buf, wr * 64 + 32, h);
            bf16x8 b0 = frag(buf, 128 + wc * 64, h);
            bf16x8 b1 = frag(buf, 128 + wc * 64 + 32, h);
            acc[0][0] = __builtin_amdgcn_mfma_f32_32x32x16_bf16(a0, b0, acc[0][0], 0, 0, 0);
            acc[0][1] = __builtin_amdgcn_mfma_f32_32x32x16_bf16(a0, b1, acc[0][1], 0, 0, 0);
            acc[1][0] = __builtin_amdgcn_mfma_f32_32x32x16_bf16(a1, b0, acc[1][0], 0, 0, 0);
            acc[1][1] = __builtin_amdgcn_mfma_f32_32x32x16_bf16(a1, b1, acc[1][1], 0, 0, 0);
        }
    }
    const float fc = (float)cnt;
    const float cinv = 1.f / fc, uinv = 1.f / (fc - 1.f);
    const float wgt = (tx == ty) ? 1.f : 2.f;
    float local = 0.f;
    #pragma unroll
    for (int i = 0; i < 2; ++i) {
        #pragma unroll
        for (int j = 0; j < 2; ++j) {
            const int gn = cn0 + wc * 64 + j * 32 + (lane & 31);
            const float mn = sums[gn] * cinv;
            #pragma unroll
            for (int r = 0; r < 16; ++r) {
                const int row = (r & 3) + 8 * (r >> 2) + 4 * q;
                const int gm = cm0 + wr * 64 + i * 32 + row;
                const float cov = (acc[i][j][r] - fc * (sums[gm] * cinv) * mn) * uinv;
                if (gm != gn) local += wgt * cov * cov;
            }
        }
    }
    for (int o = 32; o > 0; o >>= 1) local += __shfl_down(local, o, 64);
    if (lane == 0) atomicAdd(&ws[WS_COV], local);
}

__global__ __launch_bounds__(256) void k_final(const float* __restrict__ ws,
                                               float* __restrict__ out) {
    __shared__ float M[C * D];
    __shared__ float redv[4];
    __shared__ float redp[4];
    const int t = threadIdx.x;
    const int* counts = (const int*)ws + WS_COUNTS;

    float vsum = 0.f;
    for (int idx = t; idx < 2 * C * D; idx += 256) {
        const int inp = idx >> 12;
        const int cd = idx & 4095;
        const int c = cd >> 8;
        const float cnt = (float)counts[c];
        const float s  = ws[(inp ? WS_SUMS_B : WS_SUMS_A) + cd];
        const float sq = ws[(inp ? WS_SQ_B   : WS_SQ_A)   + cd];
        const float mean = s / cnt;
        const float var = (sq - cnt * mean * mean) / (cnt - 1.f);
        vsum += fmaxf(1.f - sqrtf(var + 1e-4f), 0.f);
    }
    for (int cd = t; cd < C * D; cd += 256) {
        const int c = cd >> 8;
        const float cnt = (float)counts[c];
        M[cd] = 0.5f * (ws[WS_SUMS_A + cd] + ws[WS_SUMS_B + cd]) / cnt;
    }
    for (int o = 32; o > 0; o >>= 1) vsum += __shfl_down(vsum, o, 64);
    if ((t & 63) == 0) redv[t >> 6] = vsum;
    __syncthreads();

    const int wv = t >> 6, ln = t & 63;
    float psum = 0.f;
    int p = 0;
    for (int i = 0; i < C; ++i) {
        for (int j = i + 1; j < C; ++j, ++p) {
            if ((p & 3) != wv) continue;
            float d2 = 0.f;
            #pragma unroll
            for (int d = ln; d < D; d += 64) {
                const float df = M[i * D + d] - M[j * D + d];
                d2 += df * df;
            }
            for (int o = 32; o > 0; o >>= 1) d2 += __shfl_down(d2, o, 64);
            if (ln == 0) {
                const float dist = sqrtf(d2);
                const float r = fmaxf(50.f - dist, 0.f);
                psum += r * r;
            }
        }
    }
    if (ln == 0) redp[wv] = psum;
    __syncthreads();

    if (t == 0) {
        const float var_total = redv[0] + redv[1] + redv[2] + redv[3];
        const float var_loss = var_total / 8192.f;
        const float class_sum = redp[0] + redp[1] + redp[2] + redp[3];
        const float class_loss = class_sum / 120.f;
        const float inv_loss = ws[WS_INV] / (float)(N_ROWS * D);
        const float cov_loss = 0.5f * ws[WS_COV] / (float)(C * D);
        out[0] = 25.f * inv_loss + 25.f * var_loss + 1.f * cov_loss + 50.f * class_loss;
    }
}

extern "C" void kernel_launch(void* const* d_in, const int* in_sizes, int n_in,
                              void* d_out, int out_size, void* d_ws, size_t ws_size,
                              hipStream_t stream) {
    const float* za = (const float*)d_in[0];
    const float* zb = (const float*)d_in[1];
    const int* labels = (const int*)d_in[2];
    float* out = (float*)d_out;
    float* ws = (float*)d_ws;
    int* wsi = (int*)d_ws;

    hipMemsetAsync(d_ws, 0, WS_ZERO_FLOATS * sizeof(float), stream);
    k_hist<<<128, 256, 0, stream>>>(labels, wsi + WS_COUNTS);
    k_scan<<<1, 64, 0, stream>>>(wsi + WS_COUNTS, wsi + WS_CURSOR, wsi + WS_POFFP);
    k_scatter<<<128, 256, 0, stream>>>(labels, wsi + WS_CURSOR, wsi + WS_PERM);

    if (ws_size >= NEED_A) {
        k_pack<<<MAXPAN, 256, 0, stream>>>(za, zb, wsi + WS_PERM,
                                           wsi + WS_COUNTS, wsi + WS_POFFP, ws);
        k_reduce<<<dim3(C, 4), 256, 0, stream>>>(wsi + WS_POFFP, ws);
        k_gram_split<<<dim3(3 * NSPLIT, C, 2), 256, 0, stream>>>(wsi + WS_POFFP, ws);
        k_cov<<<dim3(3, C, 2), 256, 0, stream>>>(wsi + WS_COUNTS, ws);
    } else if (ws_size >= NEED_C) {
        k_pack<<<MAXPAN, 256, 0, stream>>>(za, zb, wsi + WS_PERM,
                                           wsi + WS_COUNTS, wsi + WS_POFFP, ws);
        k_reduce<<<dim3(C, 4), 256, 0, stream>>>(wsi + WS_POFFP, ws);
        k_gram_fast<<<dim3(3, C, 2), 256, 0, stream>>>(wsi + WS_COUNTS,
                                                       wsi + WS_POFFP, ws);
    } else {
        k_stats<<<64, 256, 0, stream>>>(za, zb, labels, ws);
        k_gram_slow<<<dim3(3, C, 2), 256, 0, stream>>>(za, zb, wsi + WS_PERM,
                                                       wsi + WS_COUNTS, ws);
    }
    k_final<<<1, 256, 0, stream>>>(ws, out);
}

// Round 5
// 242.426 us; speedup vs baseline: 1.0469x; 1.0469x over previous
//
#include <hip/hip_runtime.h>
#include <math.h>

#define N_ROWS 32768
#define D 256
#define C 16

// workspace layout in floats
#define WS_SUMS_A 0
#define WS_SQ_A   4096
#define WS_SUMS_B 8192
#define WS_SQ_B   12288
#define WS_INV    16384
#define WS_COV    16385
#define WS_COUNTS 16392   /* int[16] */
#define WS_CURSOR 16408   /* int[16] */
#define WS_POFFP  16424   /* int[17] padded-panel offsets */
#define WS_PERM   16640   /* int[32768] */
#define WS_ZERO_FLOATS 16408

#define MAXPAN   1040     /* >= sum_c ceil(cnt_c/32) (<=1039) */
#define PANEL_DW 5120     /* 256 cols * 20 dwords (16 data + 4 pad) */

#define WS_PSUM   49408                      /* [MAXPAN][4][256] f32 partial stats */
#define PSUM_SZ   (MAXPAN * 1024)
#define WS_PANELS (WS_PSUM + PSUM_SZ)        /* 1,114,368 */
#define WS_GPART  (WS_PANELS + 2 * MAXPAN * PANEL_DW)   /* 11,763,968 */
#define GP_TILE   16384
#define GP_PER_SPLIT (3 * C * 2 * GP_TILE)   /* 1,572,864 floats */
#define NSPLIT    4

#define NEED_A ((size_t)(WS_GPART + NSPLIT * GP_PER_SPLIT) * 4)   /* ~72.2 MB */
#define NEED_C ((size_t)WS_GPART * 4)                              /* ~47.1 MB */

typedef __attribute__((ext_vector_type(8))) __bf16 bf16x8;
typedef __attribute__((ext_vector_type(16))) float f32x16;

__device__ inline unsigned bf16_rne(float f) {
    unsigned u = __float_as_uint(f);
    return (u + 0x7fffu + ((u >> 16) & 1u)) >> 16;
}
__device__ inline unsigned pack_bf16(float lo, float hi) {
    return bf16_rne(lo) | (bf16_rne(hi) << 16);
}

__global__ __launch_bounds__(256) void k_hist(const int* __restrict__ labels,
                                              int* __restrict__ counts) {
    __shared__ int h[C];
    const int t = threadIdx.x;
    if (t < C) h[t] = 0;
    __syncthreads();
    const int i = blockIdx.x * 256 + t;
    atomicAdd(&h[labels[i]], 1);
    __syncthreads();
    if (t < C) atomicAdd(&counts[t], h[t]);
}

__global__ void k_scan(const int* __restrict__ counts, int* __restrict__ cursor,
                       int* __restrict__ poffp) {
    if (threadIdx.x == 0) {
        int off = 0, po = 0;
        for (int c = 0; c < C; ++c) {
            cursor[c] = off;
            poffp[c] = po;
            off += counts[c];
            po += (counts[c] + 31) >> 5;
        }
        poffp[C] = po;
    }
}

__global__ __launch_bounds__(256) void k_scatter(const int* __restrict__ labels,
                                                 int* __restrict__ cursor,
                                                 int* __restrict__ perm) {
    __shared__ int lh[C];
    __shared__ int lbase[C];
    const int t = threadIdx.x;
    if (t < C) lh[t] = 0;
    __syncthreads();
    const int i = blockIdx.x * 256 + t;
    const int lab = labels[i];
    const int lr = atomicAdd(&lh[lab], 1);
    __syncthreads();
    if (t < C) lbase[t] = atomicAdd(&cursor[t], lh[t]);
    __syncthreads();
    perm[lbase[lab] + lr] = i;
}

// One block per (class, 32-row kstep) panel. Single-phase: gathers 32 rows of
// BOTH inputs with all 16 float4 loads in flight (launch_bounds(256,2) gives
// the allocator VGPR headroom; LDS at 67KB caps us at 2 blocks/CU anyway),
// one data barrier, one column pass emitting both bf16 panels + 4 stat
// partial vectors + inv_loss.
__global__ __launch_bounds__(256, 2) void k_pack(const float* __restrict__ za,
                                                 const float* __restrict__ zb,
                                                 const int* __restrict__ perm,
                                                 const int* __restrict__ counts,
                                                 const int* __restrict__ poffp,
                                                 float* __restrict__ ws) {
    const int t = threadIdx.x;
    const int blk = blockIdx.x;
    __shared__ int sh[4];
    __shared__ __align__(16) float Ta[32][261];   // +5 pad: conflict-free (meas. R3/R4)
    __shared__ __align__(16) float Tb[32][261];
    if (t == 0) {
        int c = 0;
        while (c < C && poffp[c + 1] <= blk) ++c;
        int eoff = 0;
        for (int i = 0; i < c && i < C; ++i) eoff += counts[i];
        sh[0] = c;
        sh[1] = (c < C) ? (blk - poffp[c]) : 0;
        sh[2] = eoff;
        sh[3] = (c < C) ? counts[c] : 0;
    }
    __syncthreads();
    const int cls = sh[0];
    if (cls >= C) return;
    const int kstep = sh[1], eoff = sh[2], cnt = sh[3];

    const int r = t >> 3, c8 = t & 7;            // 32 rows x 8 col-chunks
    const int lrow = kstep * 32 + r;
    const int src = (lrow < cnt) ? perm[eoff + lrow] : -1;

    float4 va[8], vb[8];
    #pragma unroll
    for (int j = 0; j < 8; ++j) {
        if (src >= 0) {
            va[j] = *(const float4*)(za + (size_t)src * D + (c8 + 8 * j) * 4);
            vb[j] = *(const float4*)(zb + (size_t)src * D + (c8 + 8 * j) * 4);
        } else {
            va[j] = make_float4(0.f, 0.f, 0.f, 0.f);
            vb[j] = make_float4(0.f, 0.f, 0.f, 0.f);
        }
    }
    float invp = 0.f;
    #pragma unroll
    for (int j = 0; j < 8; ++j) {
        const float dx = va[j].x - vb[j].x, dy = va[j].y - vb[j].y;
        const float dz = va[j].z - vb[j].z, dw = va[j].w - vb[j].w;
        invp += dx * dx + dy * dy + dz * dz + dw * dw;
    }
    #pragma unroll
    for (int j = 0; j < 8; ++j) {
        *(float4*)&Ta[r][4 * (c8 + 8 * j)] = va[j];
        *(float4*)&Tb[r][4 * (c8 + 8 * j)] = vb[j];
    }
    __syncthreads();

    // column pass: thread t owns column t of both inputs
    float s1a = 0.f, s2a = 0.f, s1b = 0.f, s2b = 0.f;
    unsigned pwa[16], pwb[16];
    #pragma unroll
    for (int w = 0; w < 16; ++w) {
        const float a0 = Ta[2 * w][t], a1 = Ta[2 * w + 1][t];
        const float b0 = Tb[2 * w][t], b1 = Tb[2 * w + 1][t];
        s1a += a0 + a1;  s2a += a0 * a0 + a1 * a1;
        s1b += b0 + b1;  s2b += b0 * b0 + b1 * b1;
        pwa[w] = pack_bf16(a0, a1);
        pwb[w] = pack_bf16(b0, b1);
    }
    // contention-free stat partials [blk][4][256]
    ws[WS_PSUM + (size_t)blk * 1024 + 0 * 256 + t] = s1a;
    ws[WS_PSUM + (size_t)blk * 1024 + 1 * 256 + t] = s2a;
    ws[WS_PSUM + (size_t)blk * 1024 + 2 * 256 + t] = s1b;
    ws[WS_PSUM + (size_t)blk * 1024 + 3 * 256 + t] = s2b;
    // panels (write full 80B stride incl. pad -> fully-lined region)
    unsigned* panels = (unsigned*)(ws + WS_PANELS);
    unsigned* pa = panels + ((size_t)0 * MAXPAN + blk) * PANEL_DW + t * 20;
    *(uint4*)(pa + 0)  = make_uint4(pwa[0],  pwa[1],  pwa[2],  pwa[3]);
    *(uint4*)(pa + 4)  = make_uint4(pwa[4],  pwa[5],  pwa[6],  pwa[7]);
    *(uint4*)(pa + 8)  = make_uint4(pwa[8],  pwa[9],  pwa[10], pwa[11]);
    *(uint4*)(pa + 12) = make_uint4(pwa[12], pwa[13], pwa[14], pwa[15]);
    *(uint4*)(pa + 16) = make_uint4(0u, 0u, 0u, 0u);
    unsigned* pb = panels + ((size_t)1 * MAXPAN + blk) * PANEL_DW + t * 20;
    *(uint4*)(pb + 0)  = make_uint4(pwb[0],  pwb[1],  pwb[2],  pwb[3]);
    *(uint4*)(pb + 4)  = make_uint4(pwb[4],  pwb[5],  pwb[6],  pwb[7]);
    *(uint4*)(pb + 8)  = make_uint4(pwb[8],  pwb[9],  pwb[10], pwb[11]);
    *(uint4*)(pb + 12) = make_uint4(pwb[12], pwb[13], pwb[14], pwb[15]);
    *(uint4*)(pb + 16) = make_uint4(0u, 0u, 0u, 0u);

    for (int o = 32; o > 0; o >>= 1) invp += __shfl_down(invp, o, 64);
    if ((t & 63) == 0) atomicAdd(&ws[WS_INV], invp);
}

// Fold per-panel stat partials into the class stats (coalesced, no atomics).
__global__ __launch_bounds__(256) void k_reduce(const int* __restrict__ poffp,
                                                float* __restrict__ ws) {
    const int t = threadIdx.x;
    const int c = blockIdx.x, s = blockIdx.y;    // s: 0=sumA,1=sqA,2=sumB,3=sqB
    float acc = 0.f;
    const int p0 = poffp[c], p1 = poffp[c + 1];
    for (int p = p0; p < p1; ++p)
        acc += ws[WS_PSUM + (size_t)p * 1024 + s * 256 + t];
    const int base = (s == 0) ? WS_SUMS_A : (s == 1) ? WS_SQ_A
                   : (s == 2) ? WS_SUMS_B : WS_SQ_B;
    ws[base + c * D + t] = acc;
}

// Split-K MFMA Gram: each block accumulates a K-chunk of one 128x128 tile and
// writes its f32 partial (no atomics) to the GPART region.
__global__ __launch_bounds__(256) void k_gram_split(const int* __restrict__ poffp,
                                                    float* __restrict__ ws) {
    const int t = threadIdx.x;
    const int tile = blockIdx.x % 3;          // 0,1,2 -> (0,0),(0,1),(1,1)
    const int split = blockIdx.x / 3;
    const int tx = tile >> 1, ty = (tile + 1) >> 1;
    const int cls = blockIdx.y, inp = blockIdx.z;
    const int p0 = poffp[cls];
    const int nsteps = poffp[cls + 1] - p0;
    const int chunk = (nsteps + NSPLIT - 1) / NSPLIT;
    const int sb = split * chunk;
    const int se = min(sb + chunk, nsteps);
    const unsigned* panels = (const unsigned*)(ws + WS_PANELS)
                           + (size_t)(inp * MAXPAN + p0) * PANEL_DW;
    const int cm0 = tx * 128, cn0 = ty * 128;
    const bool diag = (tx == ty);

    __shared__ __align__(16) unsigned lds[2][2][2560];   // 40 KB

    const int lane = t & 63, w = t >> 6;
    const int wr = w & 1, wc = w >> 1;
    const int cg = lane & 31, q = lane >> 5;

    f32x16 acc[2][2];
    #pragma unroll
    for (int i = 0; i < 2; ++i)
        #pragma unroll
        for (int j = 0; j < 2; ++j) acc[i][j] = 0.0f;

    auto stage = [&](int buf, int s) {
        const unsigned* base = panels + (size_t)s * PANEL_DW;
        {
            const unsigned* srcp = base + cm0 * 20;
            for (int u = t; u < 640; u += 256)
                __builtin_amdgcn_global_load_lds(
                    (const __attribute__((address_space(1))) unsigned*)(srcp + u * 4),
                    (__attribute__((address_space(3))) unsigned*)(&lds[buf][0][u * 4]),
                    16, 0, 0);
        }
        if (!diag) {
            const unsigned* srcp = base + cn0 * 20;
            for (int u = t; u < 640; u += 256)
                __builtin_amdgcn_global_load_lds(
                    (const __attribute__((address_space(1))) unsigned*)(srcp + u * 4),
                    (__attribute__((address_space(3))) unsigned*)(&lds[buf][1][u * 4]),
                    16, 0, 0);
        }
    };

    const int bch = diag ? 0 : 1;
    if (sb < se) {
        stage(0, sb);
        __syncthreads();
        for (int s = sb; s < se; ++s) {
            const int buf = (s - sb) & 1;
            if (s + 1 < se) stage(buf ^ 1, s + 1);   // DMA progresses during MFMA
            #pragma unroll
            for (int h = 0; h < 2; ++h) {
                bf16x8 a0 = *(const bf16x8*)&lds[buf][0][(wr * 64 + cg) * 20 + h * 8 + q * 4];
                bf16x8 a1 = *(const bf16x8*)&lds[buf][0][(wr * 64 + 32 + cg) * 20 + h * 8 + q * 4];
                bf16x8 b0 = *(const bf16x8*)&lds[buf][bch][(wc * 64 + cg) * 20 + h * 8 + q * 4];
                bf16x8 b1 = *(const bf16x8*)&lds[buf][bch][(wc * 64 + 32 + cg) * 20 + h * 8 + q * 4];
                acc[0][0] = __builtin_amdgcn_mfma_f32_32x32x16_bf16(a0, b0, acc[0][0], 0, 0, 0);
                acc[0][1] = __builtin_amdgcn_mfma_f32_32x32x16_bf16(a0, b1, acc[0][1], 0, 0, 0);
                acc[1][0] = __builtin_amdgcn_mfma_f32_32x32x16_bf16(a1, b0, acc[1][0], 0, 0, 0);
                acc[1][1] = __builtin_amdgcn_mfma_f32_32x32x16_bf16(a1, b1, acc[1][1], 0, 0, 0);
            }
            __syncthreads();
        }
    }

    float* gp = ws + WS_GPART
              + ((size_t)(split * 3 + tile) * C * 2 + cls * 2 + inp) * GP_TILE;
    #pragma unroll
    for (int i = 0; i < 2; ++i)
        #pragma unroll
        for (int j = 0; j < 2; ++j)
            #pragma unroll
            for (int r = 0; r < 16; ++r) {
                const int row = wr * 64 + i * 32 + (r & 3) + 8 * (r >> 2) + 4 * q;
                const int col = wc * 64 + j * 32 + cg;
                gp[row * 128 + col] = acc[i][j][r];
            }
}

// Sum split partials, form cov, accumulate weighted off-diagonal cov^2.
__global__ __launch_bounds__(256) void k_cov(const int* __restrict__ counts,
                                             float* __restrict__ ws) {
    const int t = threadIdx.x;
    const int tile = blockIdx.x;
    const int tx = tile >> 1, ty = (tile + 1) >> 1;
    const int cls = blockIdx.y, inp = blockIdx.z;
    const int cnt = counts[cls];
    const float fc = (float)cnt;
    const float cinv = 1.f / fc, uinv = 1.f / (fc - 1.f);
    const float wgt = (tx == ty) ? 1.f : 2.f;
    const int cm0 = tx * 128, cn0 = ty * 128;
    __shared__ float M[D];
    const float* sums = ws + (inp ? WS_SUMS_B : WS_SUMS_A) + cls * D;
    M[t] = sums[t] * cinv;
    __syncthreads();

    const float* gp0 = ws + WS_GPART + ((size_t)tile * C * 2 + cls * 2 + inp) * GP_TILE;
    float local = 0.f;
    #pragma unroll 4
    for (int k = 0; k < 64; ++k) {
        const int e = k * 256 + t;
        float g = 0.f;
        #pragma unroll
        for (int s = 0; s < NSPLIT; ++s)
            g += gp0[(size_t)s * GP_PER_SPLIT + e];
        const int row = e >> 7, col = e & 127;
        const int gm = cm0 + row, gn = cn0 + col;
        const float cov = (g - fc * M[gm] * M[gn]) * uinv;
        if (gm != gn) local += wgt * cov * cov;
    }
    for (int o = 32; o > 0; o >>= 1) local += __shfl_down(local, o, 64);
    __shared__ float red[4];
    if ((t & 63) == 0) red[t >> 6] = local;
    __syncthreads();
    if (t == 0) atomicAdd(&ws[WS_COV], red[0] + red[1] + red[2] + red[3]);
}

// Full-K gram (tier C: ws too small for split partials).
__global__ __launch_bounds__(256) void k_gram_fast(const int* __restrict__ counts,
                                                   const int* __restrict__ poffp,
                                                   float* __restrict__ ws) {
    const int t = threadIdx.x;
    const int tile = blockIdx.x;
    const int tx = tile >> 1, ty = (tile + 1) >> 1;
    const int cls = blockIdx.y, inp = blockIdx.z;
    const int cnt = counts[cls];
    const int p0 = poffp[cls];
    const int nsteps = poffp[cls + 1] - p0;
    if (nsteps == 0) return;
    const float* sums = ws + (inp ? WS_SUMS_B : WS_SUMS_A) + cls * D;
    const unsigned* panels = (const unsigned*)(ws + WS_PANELS)
                           + (size_t)(inp * MAXPAN + p0) * PANEL_DW;
    const int cm0 = tx * 128, cn0 = ty * 128;
    const bool diag = (tx == ty);
    __shared__ __align__(16) unsigned lds[2][2][2560];
    const int lane = t & 63, w = t >> 6;
    const int wr = w & 1, wc = w >> 1;
    const int cg = lane & 31, q = lane >> 5;
    f32x16 acc[2][2];
    #pragma unroll
    for (int i = 0; i < 2; ++i)
        #pragma unroll
        for (int j = 0; j < 2; ++j) acc[i][j] = 0.0f;
    auto stage = [&](int buf, int s) {
        const unsigned* base = panels + (size_t)s * PANEL_DW;
        {
            const unsigned* srcp = base + cm0 * 20;
            for (int u = t; u < 640; u += 256)
                __builtin_amdgcn_global_load_lds(
                    (const __attribute__((address_space(1))) unsigned*)(srcp + u * 4),
                    (__attribute__((address_space(3))) unsigned*)(&lds[buf][0][u * 4]),
                    16, 0, 0);
        }
        if (!diag) {
            const unsigned* srcp = base + cn0 * 20;
            for (int u = t; u < 640; u += 256)
                __builtin_amdgcn_global_load_lds(
                    (const __attribute__((address_space(1))) unsigned*)(srcp + u * 4),
                    (__attribute__((address_space(3))) unsigned*)(&lds[buf][1][u * 4]),
                    16, 0, 0);
        }
    };
    const int bch = diag ? 0 : 1;
    stage(0, 0);
    __syncthreads();
    for (int s = 0; s < nsteps; ++s) {
        const int buf = s & 1;
        if (s + 1 < nsteps) stage(buf ^ 1, s + 1);
        #pragma unroll
        for (int h = 0; h < 2; ++h) {
            bf16x8 a0 = *(const bf16x8*)&lds[buf][0][(wr * 64 + cg) * 20 + h * 8 + q * 4];
            bf16x8 a1 = *(const bf16x8*)&lds[buf][0][(wr * 64 + 32 + cg) * 20 + h * 8 + q * 4];
            bf16x8 b0 = *(const bf16x8*)&lds[buf][bch][(wc * 64 + cg) * 20 + h * 8 + q * 4];
            bf16x8 b1 = *(const bf16x8*)&lds[buf][bch][(wc * 64 + 32 + cg) * 20 + h * 8 + q * 4];
            acc[0][0] = __builtin_amdgcn_mfma_f32_32x32x16_bf16(a0, b0, acc[0][0], 0, 0, 0);
            acc[0][1] = __builtin_amdgcn_mfma_f32_32x32x16_bf16(a0, b1, acc[0][1], 0, 0, 0);
            acc[1][0] = __builtin_amdgcn_mfma_f32_32x32x16_bf16(a1, b0, acc[1][0], 0, 0, 0);
            acc[1][1] = __builtin_amdgcn_mfma_f32_32x32x16_bf16(a1, b1, acc[1][1], 0, 0, 0);
        }
        __syncthreads();
    }
    const float fc = (float)cnt;
    const float cinv = 1.f / fc, uinv = 1.f / (fc - 1.f);
    const float wgt = diag ? 1.f : 2.f;
    float local = 0.f;
    #pragma unroll
    for (int i = 0; i < 2; ++i) {
        #pragma unroll
        for (int j = 0; j < 2; ++j) {
            const int gn = cn0 + wc * 64 + j * 32 + (lane & 31);
            const float mn = sums[gn] * cinv;
            #pragma unroll
            for (int r = 0; r < 16; ++r) {
                const int row = (r & 3) + 8 * (r >> 2) + 4 * q;
                const int gm = cm0 + wr * 64 + i * 32 + row;
                const float cov = (acc[i][j][r] - fc * (sums[gm] * cinv) * mn) * uinv;
                if (gm != gn) local += wgt * cov * cov;
            }
        }
    }
    for (int o = 32; o > 0; o >>= 1) local += __shfl_down(local, o, 64);
    if (lane == 0) atomicAdd(&ws[WS_COV], local);
}

// ---------------- tier D fallback (tiny ws): round-2 kernels ----------------
__global__ __launch_bounds__(256) void k_stats(const float* __restrict__ za,
                                               const float* __restrict__ zb,
                                               const int* __restrict__ labels,
                                               float* __restrict__ ws) {
    const int t = threadIdx.x;
    __shared__ float S[4][C * D];
    __shared__ int lab[512];
    for (int i = t; i < 4 * C * D; i += 256) ((float*)S)[i] = 0.f;
    const int r0 = blockIdx.x * 512;
    for (int i = t; i < 512; i += 256) lab[i] = labels[r0 + i];
    __syncthreads();
    float invp = 0.f;
    #pragma unroll 4
    for (int rr = 0; rr < 512; ++rr) {
        const int l = lab[rr];
        const float a = za[(size_t)(r0 + rr) * D + t];
        const float b = zb[(size_t)(r0 + rr) * D + t];
        const float dd = a - b;
        invp += dd * dd;
        S[0][l * D + t] += a;
        S[1][l * D + t] += a * a;
        S[2][l * D + t] += b;
        S[3][l * D + t] += b * b;
    }
    __syncthreads();
    #pragma unroll
    for (int c = 0; c < C; ++c) {
        atomicAdd(&ws[WS_SUMS_A + c * D + t], S[0][c * D + t]);
        atomicAdd(&ws[WS_SQ_A   + c * D + t], S[1][c * D + t]);
        atomicAdd(&ws[WS_SUMS_B + c * D + t], S[2][c * D + t]);
        atomicAdd(&ws[WS_SQ_B   + c * D + t], S[3][c * D + t]);
    }
    for (int o = 32; o > 0; o >>= 1) invp += __shfl_down(invp, o, 64);
    if ((t & 63) == 0) atomicAdd(&ws[WS_INV], invp);
}

#define STR 20
#define KB 32
__global__ __launch_bounds__(256) void k_gram_slow(const float* __restrict__ za,
                                                   const float* __restrict__ zb,
                                                   const int* __restrict__ perm,
                                                   const int* __restrict__ counts,
                                                   float* __restrict__ ws) {
    const int t = threadIdx.x;
    const int tile = blockIdx.x;
    const int tx = tile >> 1, ty = (tile + 1) >> 1;
    const int cls = blockIdx.y;
    const int inp = blockIdx.z;
    const float* X = inp ? zb : za;
    const float* sums = ws + (inp ? WS_SUMS_B : WS_SUMS_A) + cls * D;
    int offs = 0;
    for (int c = 0; c < cls; ++c) offs += counts[c];
    const int cnt = counts[cls];
    const int cm0 = tx * 128, cn0 = ty * 128;
    __shared__ __align__(16) unsigned lds[2][256 * STR];
    const int p = t >> 5, cq = t & 31;
    const int lane = t & 63, w = t >> 6;
    const int wr = w & 1, wc = w >> 1;
    const int cg = lane & 31, q = lane >> 5;
    f32x16 acc[2][2];
    #pragma unroll
    for (int i = 0; i < 2; ++i)
        #pragma unroll
        for (int j = 0; j < 2; ++j) acc[i][j] = 0.0f;
    const int nsteps = (cnt + KB - 1) / KB;
    auto stage = [&](int buf, int k0) {
        #pragma unroll
        for (int ch = 0; ch < 2; ++ch) {
            const int gc = (ch ? cn0 : cm0) + 4 * cq;
            #pragma unroll
            for (int sub = 0; sub < 2; ++sub) {
                const int rr = sub * 16 + 2 * p;
                const int r0 = k0 + rr, r1 = r0 + 1;
                float4 v0 = make_float4(0.f, 0.f, 0.f, 0.f), v1 = v0;
                if (r0 < cnt) v0 = *(const float4*)(X + (size_t)perm[offs + r0] * D + gc);
                if (r1 < cnt) v1 = *(const float4*)(X + (size_t)perm[offs + r1] * D + gc);
                unsigned* dst = &lds[buf][(ch * 128 + 4 * cq) * STR + (rr >> 1)];
                dst[0 * STR] = pack_bf16(v0.x, v1.x);
                dst[1 * STR] = pack_bf16(v0.y, v1.y);
                dst[2 * STR] = pack_bf16(v0.z, v1.z);
                dst[3 * STR] = pack_bf16(v0.w, v1.w);
            }
        }
    };
    auto frag = [&](int buf, int colbase, int h) -> bf16x8 {
        return *(const bf16x8*)&lds[buf][(colbase + cg) * STR + h * 8 + q * 4];
    };
    stage(0, 0);
    for (int s = 0; s < nsteps; ++s) {
        __syncthreads();
        const int buf = s & 1;
        if (s + 1 < nsteps) stage(buf ^ 1, (s + 1) * KB);
        #pragma unroll
        for (int h = 0; h < 2; ++h) {
            bf16x8 a0 = frag(buf, wr * 64, h);
            bf16x8 a1 = frag(buf, wr * 64 + 32, h);
            bf16x8 b0 = frag(buf, 128 + wc * 64, h);
            bf16x8 b1 = frag(buf, 128 + wc * 64 + 32, h);
            acc[0][0] = __builtin_amdgcn_mfma_f32_32x32x16_bf16(a0, b0, acc[0][0], 0, 0, 0);
            acc[0][1] = __builtin_amdgcn_mfma_f32_32x32x16_bf16(a0, b1, acc[0][1], 0, 0, 0);
            acc[1][0] = __builtin_amdgcn_mfma_f32_32x32x16_bf16(a1, b0, acc[1][0], 0, 0, 0);
            acc[1][1] = __builtin_amdgcn_mfma_f32_32x32x16_bf16(a1, b1, acc[1][1], 0, 0, 0);
        }
    }
    const float fc = (float)cnt;
    const float cinv = 1.f / fc, uinv = 1.f / (fc - 1.f);
    const float wgt = (tx == ty) ? 1.f : 2.f;
    float local = 0.f;
    #pragma unroll
    for (int i = 0; i < 2; ++i) {
        #pragma unroll
        for (int j = 0; j < 2; ++j) {
            const int gn = cn0 + wc * 64 + j * 32 + (lane & 31);
            const float mn = sums[gn] * cinv;
            #pragma unroll
            for (int r = 0; r < 16; ++r) {
                const int row = (r & 3) + 8 * (r >> 2) + 4 * q;
                const int gm = cm0 + wr * 64 + i * 32 + row;
                const float cov = (acc[i][j][r] - fc * (sums[gm] * cinv) * mn) * uinv;
                if (gm != gn) local += wgt * cov * cov;
            }
        }
    }
    for (int o = 32; o > 0; o >>= 1) local += __shfl_down(local, o, 64);
    if (lane == 0) atomicAdd(&ws[WS_COV], local);
}

__global__ __launch_bounds__(256) void k_final(const float* __restrict__ ws,
                                               float* __restrict__ out) {
    __shared__ float M[C * D];
    __shared__ float redv[4];
    __shared__ float redp[4];
    const int t = threadIdx.x;
    const int* counts = (const int*)ws + WS_COUNTS;

    float vsum = 0.f;
    for (int idx = t; idx < 2 * C * D; idx += 256) {
        const int inp = idx >> 12;
        const int cd = idx & 4095;
        const int c = cd >> 8;
        const float cnt = (float)counts[c];
        const float s  = ws[(inp ? WS_SUMS_B : WS_SUMS_A) + cd];
        const float sq = ws[(inp ? WS_SQ_B   : WS_SQ_A)   + cd];
        const float mean = s / cnt;
        const float var = (sq - cnt * mean * mean) / (cnt - 1.f);
        vsum += fmaxf(1.f - sqrtf(var + 1e-4f), 0.f);
    }
    for (int cd = t; cd < C * D; cd += 256) {
        const int c = cd >> 8;
        const float cnt = (float)counts[c];
        M[cd] = 0.5f * (ws[WS_SUMS_A + cd] + ws[WS_SUMS_B + cd]) / cnt;
    }
    for (int o = 32; o > 0; o >>= 1) vsum += __shfl_down(vsum, o, 64);
    if ((t & 63) == 0) redv[t >> 6] = vsum;
    __syncthreads();

    const int wv = t >> 6, ln = t & 63;
    float psum = 0.f;
    int p = 0;
    for (int i = 0; i < C; ++i) {
        for (int j = i + 1; j < C; ++j, ++p) {
            if ((p & 3) != wv) continue;
            float d2 = 0.f;
            #pragma unroll
            for (int d = ln; d < D; d += 64) {
                const float df = M[i * D + d] - M[j * D + d];
                d2 += df * df;
            }
            for (int o = 32; o > 0; o >>= 1) d2 += __shfl_down(d2, o, 64);
            if (ln == 0) {
                const float dist = sqrtf(d2);
                const float r = fmaxf(50.f - dist, 0.f);
                psum += r * r;
            }
        }
    }
    if (ln == 0) redp[wv] = psum;
    __syncthreads();

    if (t == 0) {
        const float var_total = redv[0] + redv[1] + redv[2] + redv[3];
        const float var_loss = var_total / 8192.f;
        const float class_sum = redp[0] + redp[1] + redp[2] + redp[3];
        const float class_loss = class_sum / 120.f;
        const float inv_loss = ws[WS_INV] / (float)(N_ROWS * D);
        const float cov_loss = 0.5f * ws[WS_COV] / (float)(C * D);
        out[0] = 25.f * inv_loss + 25.f * var_loss + 1.f * cov_loss + 50.f * class_loss;
    }
}

extern "C" void kernel_launch(void* const* d_in, const int* in_sizes, int n_in,
                              void* d_out, int out_size, void* d_ws, size_t ws_size,
                              hipStream_t stream) {
    const float* za = (const float*)d_in[0];
    const float* zb = (const float*)d_in[1];
    const int* labels = (const int*)d_in[2];
    float* out = (float*)d_out;
    float* ws = (float*)d_ws;
    int* wsi = (int*)d_ws;

    hipMemsetAsync(d_ws, 0, WS_ZERO_FLOATS * sizeof(float), stream);
    k_hist<<<128, 256, 0, stream>>>(labels, wsi + WS_COUNTS);
    k_scan<<<1, 64, 0, stream>>>(wsi + WS_COUNTS, wsi + WS_CURSOR, wsi + WS_POFFP);
    k_scatter<<<128, 256, 0, stream>>>(labels, wsi + WS_CURSOR, wsi + WS_PERM);

    if (ws_size >= NEED_A) {
        k_pack<<<MAXPAN, 256, 0, stream>>>(za, zb, wsi + WS_PERM,
                                           wsi + WS_COUNTS, wsi + WS_POFFP, ws);
        k_reduce<<<dim3(C, 4), 256, 0, stream>>>(wsi + WS_POFFP, ws);
        k_gram_split<<<dim3(3 * NSPLIT, C, 2), 256, 0, stream>>>(wsi + WS_POFFP, ws);
        k_cov<<<dim3(3, C, 2), 256, 0, stream>>>(wsi + WS_COUNTS, ws);
    } else if (ws_size >= NEED_C) {
        k_pack<<<MAXPAN, 256, 0, stream>>>(za, zb, wsi + WS_PERM,
                                           wsi + WS_COUNTS, wsi + WS_POFFP, ws);
        k_reduce<<<dim3(C, 4), 256, 0, stream>>>(wsi + WS_POFFP, ws);
        k_gram_fast<<<dim3(3, C, 2), 256, 0, stream>>>(wsi + WS_COUNTS,
                                                       wsi + WS_POFFP, ws);
    } else {
        k_stats<<<64, 256, 0, stream>>>(za, zb, labels, ws);
        k_gram_slow<<<dim3(3, C, 2), 256, 0, stream>>>(za, zb, wsi + WS_PERM,
                                                       wsi + WS_COUNTS, ws);
    }
    k_final<<<1, 256, 0, stream>>>(ws, out);
}